// Round 15
// baseline (215.216 us; speedup 1.0000x reference)
//
#include <hip/hip_runtime.h>
#include <math.h>

typedef unsigned long long u64;
typedef unsigned int u32;
typedef unsigned short ushort_t;
typedef _Float16 half8 __attribute__((ext_vector_type(8)));
typedef float f32x4 __attribute__((ext_vector_type(4)));

// Problem constants
#define TOKENS 1024   // B*S = 2*512
#define DDIM   1024
#define NHEAD  8
#define QD     256
#define HQD    2048   // NHEAD*QD
#define NROWS  8192   // TOKENS*NHEAD
#define NKEY   128
#define TOPK   16

#define QSCALE 256.0f            // pre-scale for A and W before f16 split
#define QINVS  (1.0f / 65536.0f) // 1/(256*256), exact

__device__ __forceinline__ ushort_t f2bf(float f) {
    u32 u = __float_as_uint(f);
    u32 r = (u + 0x7FFFu + ((u >> 16) & 1u)) >> 16;   // RNE
    return (ushort_t)r;
}
__device__ __forceinline__ float bf_lo(u32 w) { return __uint_as_float(w << 16); }
__device__ __forceinline__ float bf_hi(u32 w) { return __uint_as_float(w & 0xFFFF0000u); }

// f16 2-term split: x = h + l + O(2^-24 x)
__device__ __forceinline__ void hsplit(float x, ushort_t& h, ushort_t& l) {
    _Float16 hh = (_Float16)x;          // RNE
    float r = x - (float)hh;            // exact
    _Float16 ll = (_Float16)r;
    union { _Float16 f; ushort_t u; } c1, c2;
    c1.f = hh; c2.f = ll;
    h = c1.u; l = c2.u;
}

// orderable u32 from float: larger code <=> larger float
__device__ __forceinline__ u32 ordf(float v) {
    u32 u = __float_as_uint(v);
    return (u & 0x80000000u) ? ~u : (u | 0x80000000u);
}
__device__ __forceinline__ u64 mkkey2(float v, u32 idx) {
    return ((u64)ordf(v) << 32) | (u64)(0xFFFFFFFFu - idx);
}

// One cvt work-unit = 16384 elems (gcb in [0,2048): <1024 = down, else up).
template<int NTHR, int ITERS>
__device__ __forceinline__ void cvt_chunk(int gcb, int tid,
                                          const float* __restrict__ down,
                                          const float* __restrict__ up,
                                          ushort_t* __restrict__ downb,
                                          ushort_t* __restrict__ upb) {
    const float* src = (gcb < 1024) ? down : up;
    ushort_t* dst = (gcb < 1024) ? downb : upb;
    const size_t base4 = (size_t)(gcb & 1023) * 4096;
    const float4* s4 = (const float4*)src;
    ushort4* d4 = (ushort4*)dst;
#pragma unroll 4
    for (int it = 0; it < ITERS; it++) {
        size_t i = base4 + (size_t)it * NTHR + tid;
        float4 v = s4[i];
        ushort4 o;
        o.x = f2bf(v.x); o.y = f2bf(v.y); o.z = f2bf(v.z); o.w = f2bf(v.w);
        d4[i] = o;
    }
}

// ---------------------------------------------------------------------------
// k_prep1 (256 thr):
//   [0,128):   A*256 -> f16 hi|lo  Ab[m][0:1024]=hi, [1024:2048]=lo
//   [128,640): W*256 -> transpose + f16 hi|lo  Wt[n][0:1024]=hi(k), [1024:]=lo
//   [640,768): sub_key L2-normalize (2 rows/block)
// ---------------------------------------------------------------------------
__global__ __launch_bounds__(256) void k_prep1(
    const float* __restrict__ A, const float* __restrict__ W,
    ushort_t* __restrict__ Ab, ushort_t* __restrict__ Wt,
    const float* __restrict__ sk0, const float* __restrict__ sk1,
    float* __restrict__ k0n, float* __restrict__ k1n)
{
    __shared__ __align__(16) char praw[18464];
    const int bid = blockIdx.x;
    const int tid = threadIdx.x;

    if (bid < 128) {
        // ---------------- A -> hi|lo ----------------
#pragma unroll
        for (int i = 0; i < 8; i++) {
            const int row = bid * 8 + i;
            float4 v = *(const float4*)(A + (size_t)row * 1024 + tid * 4);
            ushort4 h, l;
            hsplit(v.x * QSCALE, h.x, l.x);
            hsplit(v.y * QSCALE, h.y, l.y);
            hsplit(v.z * QSCALE, h.z, l.z);
            hsplit(v.w * QSCALE, h.w, l.w);
            *(ushort4*)(Ab + (size_t)row * 2048 + tid * 4) = h;
            *(ushort4*)(Ab + (size_t)row * 2048 + 1024 + tid * 4) = l;
        }
    } else if (bid < 640) {
        // ---------------- W transpose + hi|lo (64k x 64n tile) ----------------
        const int cb = bid - 128;                  // 0..511
        const int k0 = (cb >> 5) * 64;
        const int n0 = (cb & 31) * 64;
        ushort_t* Lh = (ushort_t*)praw;            // [64n][72]
        ushort_t* Ll = (ushort_t*)praw + 4608;
        const int nn = (tid & 15) * 4;
        const int kk = tid >> 4;                   // 0..15
#pragma unroll
        for (int p = 0; p < 4; p++) {
            const int k = kk + 16 * p;
            float4 v = *(const float4*)(W + (size_t)(k0 + k) * HQD + n0 + nn);
            float xs[4] = {v.x * QSCALE, v.y * QSCALE, v.z * QSCALE, v.w * QSCALE};
#pragma unroll
            for (int j = 0; j < 4; j++) {
                ushort_t h, l;
                hsplit(xs[j], h, l);
                Lh[(nn + j) * 72 + k] = h;
                Ll[(nn + j) * 72 + k] = l;
            }
        }
        __syncthreads();
#pragma unroll
        for (int e = 0; e < 2; e++) {
            const int idx = tid + 256 * e;
            const int n = idx >> 3, ks = idx & 7;
            uint4 hv = *(const uint4*)(Lh + n * 72 + ks * 8);
            uint4 lv = *(const uint4*)(Ll + n * 72 + ks * 8);
            *(uint4*)(Wt + (size_t)(n0 + n) * 2048 + k0 + ks * 8) = hv;
            *(uint4*)(Wt + (size_t)(n0 + n) * 2048 + 1024 + k0 + ks * 8) = lv;
        }
    } else {
        // ---------------- key L2-normalize (2 rows/block) ----------------
        float* fs = (float*)praw;
        const int b2 = bid - 640;                  // 0..127
        const int sub = tid >> 7;
        const int col = tid & 127;
        const int gr = b2 * 2 + sub;
        const float* src = (gr < 128) ? sk0 : sk1;
        float* dst = (gr < 128) ? k0n : k1n;
        const int row = gr & 127;
        float v = src[row * 128 + col];
        float sq = v * v;
        for (int off = 32; off; off >>= 1) sq += __shfl_down(sq, off);
        if ((tid & 63) == 0) fs[tid >> 6] = sq;
        __syncthreads();
        if ((tid & 127) == 0) {
            float n = sqrtf(fs[tid >> 6] + fs[(tid >> 6) + 1]);
            fs[8 + sub] = 1.0f / fmaxf(n, 1e-12f);
        }
        __syncthreads();
        dst[row * 128 + col] = v * fs[8 + sub];
    }
}

// ---------------------------------------------------------------------------
// k_fused2:
//   blocks [0,512):     qmfma 64x64 full-K f16 MFMA 3-term (verified body)
//   blocks [512,1536):  down-cvt gcb [0,1024)  (overlaps GEMM's idle HBM)
// ---------------------------------------------------------------------------
__global__ __launch_bounds__(256) void k_fused2(
    const ushort_t* __restrict__ Ab, const ushort_t* __restrict__ Wt,
    float* __restrict__ qp,
    const float* __restrict__ down, const float* __restrict__ up,
    ushort_t* __restrict__ downb, ushort_t* __restrict__ upb)
{
    __shared__ __align__(16) char lds[2][16384];   // per buf: As 8K + Bs 8K
    const int tid = threadIdx.x;
    const int bid = blockIdx.x;

    if (bid >= 512) {
        cvt_chunk<256, 16>(bid - 512, tid, down, up, downb, upb);
        return;
    }

    const int m0 = (bid >> 5) * 64;      // 16 m-tiles
    const int n0 = (bid & 31) * 64;      // 32 n-tiles

    const int srow = tid >> 2;           // 0..63 staging row
    const int scol = (tid & 3) * 16;     // ushort offset (32B chunk)
    const int swz = (srow & 7) << 4;

    const int lane = tid & 63;
    const int w = tid >> 6;
    const int wmb = (w >> 1) * 32;
    const int wnb = (w & 1) * 32;
    const int fr = lane & 15;
    const int kg = lane >> 4;
    const int rswz = (fr & 7) << 4;

    f32x4 acc[2][2];
#pragma unroll
    for (int i = 0; i < 2; i++)
#pragma unroll
        for (int j = 0; j < 2; j++)
            acc[i][j] = (f32x4){0.f, 0.f, 0.f, 0.f};

    uint4 ar0, ar1, br0, br1;

    auto LOADR = [&](int gs) {
        const int term = gs >> 4;                   // 0:HH 1:LH 2:HL
        const int aoff = (term == 1) ? 1024 : 0;
        const int woff = (term == 2) ? 1024 : 0;
        const int kb = (gs & 15) * 64;
        const ushort_t* ap = Ab + (size_t)(m0 + srow) * 2048 + aoff + kb + scol;
        const ushort_t* wp = Wt + (size_t)(n0 + srow) * 2048 + woff + kb + scol;
        ar0 = *(const uint4*)(ap);
        ar1 = *(const uint4*)(ap + 8);
        br0 = *(const uint4*)(wp);
        br1 = *(const uint4*)(wp + 8);
    };
    auto WLDS = [&](int buf) {
        char* As = lds[buf];
        char* Bs = lds[buf] + 8192;
        const int b0 = (srow * 128 + scol * 2) ^ swz;
        const int b1 = (srow * 128 + scol * 2 + 16) ^ swz;
        *(uint4*)(As + b0) = ar0;
        *(uint4*)(As + b1) = ar1;
        *(uint4*)(Bs + b0) = br0;
        *(uint4*)(Bs + b1) = br1;
    };

    LOADR(0);
    WLDS(0);

    for (int s = 0; s < 48; s++) {
        __syncthreads();                     // buf[s&1] writes visible
        if (s < 47) LOADR(s + 1);            // prefetch next into regs
        const char* As = lds[s & 1];
        const char* Bs = lds[s & 1] + 8192;
#pragma unroll
        for (int kh = 0; kh < 2; kh++) {
            half8 a[2], b[2];
#pragma unroll
            for (int f = 0; f < 2; f++) {
                const int rowA = wmb + f * 16 + fr;
                a[f] = *(const half8*)(As + ((rowA * 128 + kh * 64 + kg * 16) ^ rswz));
                const int rowB = wnb + f * 16 + fr;
                b[f] = *(const half8*)(Bs + ((rowB * 128 + kh * 64 + kg * 16) ^ rswz));
            }
#pragma unroll
            for (int fm = 0; fm < 2; fm++)
#pragma unroll
                for (int fn = 0; fn < 2; fn++)
                    acc[fm][fn] = __builtin_amdgcn_mfma_f32_16x16x32_f16(
                        a[fm], b[fn], acc[fm][fn], 0, 0, 0);
        }
        if (s < 47) WLDS((s + 1) & 1);       // write NEXT buffer (no race)
    }

#pragma unroll
    for (int fm = 0; fm < 2; fm++) {
        const int rbase = m0 + wmb + fm * 16 + kg * 4;
#pragma unroll
        for (int fn = 0; fn < 2; fn++) {
            const int c = n0 + wnb + fn * 16 + fr;
#pragma unroll
            for (int j = 0; j < 4; j++)
                qp[(size_t)(rbase + j) * HQD + c] = acc[fm][fn][j];
        }
    }
}

// ---------------------------------------------------------------------------
// K2a: stats-only column sums/sumsq of (qsc*qp+bias)  [8192][256]
// ---------------------------------------------------------------------------
__global__ __launch_bounds__(256) void k_bnstat1(const float* __restrict__ qp,
                                                 const float* __restrict__ bq,
                                                 float* __restrict__ psum,
                                                 float* __restrict__ psq,
                                                 float qsc)
{
    const int b = blockIdx.x;
    const int j = threadIdx.x;
    float s = 0.f, sq = 0.f;
#pragma unroll 4
    for (int rr = 0; rr < 16; rr++) {
        const int r = b * 16 + rr;
        const size_t g = (size_t)r * 256 + j;
        float v = qp[g] * qsc + bq[(r & 7) * 256 + j];
        s += v; sq += v * v;
    }
    psum[b * 256 + j] = s;
    psq[b * 256 + j]  = sq;
}

// K2b: finish stats -> mean[j], scale[j] = gamma/sqrt(var+eps)
// 8 blocks x 256 thr
__global__ __launch_bounds__(256) void k_bnstat2(const float* __restrict__ psum,
                                                 const float* __restrict__ psq,
                                                 const float* __restrict__ gamma,
                                                 float* __restrict__ meanOut,
                                                 float* __restrict__ scaleOut)
{
    __shared__ float ls[8][64];   // [seg][2*32]
    const int col = blockIdx.x * 32 + (threadIdx.x & 31);
    const int seg = threadIdx.x >> 5;
    float s = 0.f, sq = 0.f;
    for (int b = seg; b < 512; b += 8) {
        s += psum[b * 256 + col];
        sq += psq[b * 256 + col];
    }
    ls[seg][(threadIdx.x & 31)] = s;
    ls[seg][32 + (threadIdx.x & 31)] = sq;
    __syncthreads();
    if (threadIdx.x < 32) {
        float ts = 0.f, tq = 0.f;
#pragma unroll
        for (int g = 0; g < 8; g++) {
            ts += ls[g][threadIdx.x];
            tq += ls[g][32 + threadIdx.x];
        }
        float mean = ts * (1.0f / 8192.0f);
        float var = tq * (1.0f / 8192.0f) - mean * mean;
        meanOut[col] = mean;
        scaleOut[col] = gamma[col] / sqrtf(var + 1e-5f);
    }
}

// ---------------------------------------------------------------------------
// K4: fused BN + per-half L2-norm + scores. 1D grid:
//   blocks [0,256): scores (half = bid>>7, row0 = (bid&127)*64)
//   blocks [256,768): up-cvt gcb [1024,1536)
// ---------------------------------------------------------------------------
__global__ __launch_bounds__(256) void k_scores(const float* __restrict__ qp,
                                                const float* __restrict__ bq,
                                                const float* __restrict__ mean,
                                                const float* __restrict__ scale,
                                                const float* __restrict__ beta,
                                                const float* __restrict__ kn0,
                                                const float* __restrict__ kn1,
                                                float* __restrict__ sOut0,
                                                float* __restrict__ sOut1,
                                                float qsc,
                                                const float* __restrict__ down,
                                                const float* __restrict__ up,
                                                ushort_t* __restrict__ downb,
                                                ushort_t* __restrict__ upb)
{
    __shared__ float Qs[128 * 68];   // [d][r]
    __shared__ float Ks[64 * 132];   // [d][n]
    __shared__ float rp[4][64];
    __shared__ float invn[64];
    const int bid = blockIdx.x;
    const int tid = threadIdx.x;
    if (bid >= 256) {
        cvt_chunk<256, 16>(1024 + (bid - 256), tid, down, up, downb, upb);
        return;
    }
    const int half = bid >> 7;
    const int row0 = (bid & 127) * 64;

    // ---- stage BN-transformed Q (full 128-dim half-rows) ----
    {
        const int d4 = (tid & 31) * 4;       // 0..124
        const int rbase = tid >> 5;          // 0..7 (head index of its rows)
        const int j4 = half * 128 + d4;
        float4 m4 = *(const float4*)(mean + j4);
        float4 sc4 = *(const float4*)(scale + j4);
        float4 be4 = *(const float4*)(beta + j4);
        float4 bi4 = *(const float4*)(bq + rbase * 256 + j4);
#pragma unroll
        for (int p = 0; p < 8; p++) {
            const int rr = rbase + p * 8;
            const int row = row0 + rr;                  // (row&7)==rbase
            const size_t g = (size_t)(row >> 3) * 2048 + (size_t)rbase * 256 + j4;
            float4 a = *(const float4*)(qp + g);
            float x0 = (a.x * qsc + bi4.x - m4.x) * sc4.x + be4.x;
            float x1 = (a.y * qsc + bi4.y - m4.y) * sc4.y + be4.y;
            float x2 = (a.z * qsc + bi4.z - m4.z) * sc4.z + be4.z;
            float x3 = (a.w * qsc + bi4.w - m4.w) * sc4.w + be4.w;
            Qs[(d4 + 0) * 68 + rr] = x0;
            Qs[(d4 + 1) * 68 + rr] = x1;
            Qs[(d4 + 2) * 68 + rr] = x2;
            Qs[(d4 + 3) * 68 + rr] = x3;
        }
    }
    __syncthreads();
    // ---- per-row sumsq -> invnorm ----
    {
        const int r = tid & 63, qd = tid >> 6;
        float s = 0.f;
#pragma unroll 8
        for (int d = qd * 32; d < qd * 32 + 32; d++) {
            float v = Qs[d * 68 + r];
            s += v * v;
        }
        rp[qd][r] = s;
    }
    __syncthreads();
    if (tid < 64) {
        float s = rp[0][tid] + rp[1][tid] + rp[2][tid] + rp[3][tid];
        invn[tid] = 1.0f / fmaxf(sqrtf(s), 1e-12f);
    }

    const float* kn = half ? kn1 : kn0;
    float* sOut = half ? sOut1 : sOut0;
    const int ty = tid >> 5;   // 0..7  -> r = ty*8
    const int tx = tid & 31;   // 0..31 -> n = tx*4
    float acc[8][4] = {};

    for (int c = 0; c < 2; c++) {
        __syncthreads();
        {
            int dd4 = (tid & 15) * 4;
            int n = tid >> 4;  // 0..15
#pragma unroll
            for (int p = 0; p < 8; p++) {
                int nn = n + p * 16;
                float4 v = *(const float4*)(kn + nn * 128 + c * 64 + dd4);
                Ks[(dd4 + 0) * 132 + nn] = v.x; Ks[(dd4 + 1) * 132 + nn] = v.y;
                Ks[(dd4 + 2) * 132 + nn] = v.z; Ks[(dd4 + 3) * 132 + nn] = v.w;
            }
        }
        __syncthreads();
#pragma unroll
        for (int d = 0; d < 64; d++) {
            float a[8], b[4];
            *(float4*)(a)     = *(const float4*)&Qs[(c * 64 + d) * 68 + ty * 8];
            *(float4*)(a + 4) = *(const float4*)&Qs[(c * 64 + d) * 68 + ty * 8 + 4];
            *(float4*)(b)     = *(const float4*)&Ks[d * 132 + tx * 4];
#pragma unroll
            for (int i = 0; i < 8; i++)
#pragma unroll
                for (int j = 0; j < 4; j++)
                    acc[i][j] = fmaf(a[i], b[j], acc[i][j]);
        }
    }
#pragma unroll
    for (int i = 0; i < 8; i++) {
        const float iv = invn[ty * 8 + i];
        float4 r;
        r.x = acc[i][0] * iv; r.y = acc[i][1] * iv;
        r.z = acc[i][2] * iv; r.w = acc[i][3] * iv;
        *(float4*)(sOut + (size_t)(row0 + ty * 8 + i) * 128 + tx * 4) = r;
    }
}

// ---------------------------------------------------------------------------
// K4c: exact top-16 + softmax via ballot-radix threshold selection.
//   blocks [0,2048): topk (4 rows/block, one wave each)
//   blocks [2048,2560): up-cvt gcb [1536,2048)
// ---------------------------------------------------------------------------
__global__ __launch_bounds__(256) void k_topk(const float* __restrict__ s0,
                                              const float* __restrict__ s1,
                                              int* __restrict__ tIdx,
                                              float* __restrict__ tW,
                                              const float* __restrict__ down,
                                              const float* __restrict__ up,
                                              ushort_t* __restrict__ downb,
                                              ushort_t* __restrict__ upb)
{
    __shared__ float shv[4][2][16];
    __shared__ int   shi[4][2][16];
    __shared__ float swv[4][16];
    __shared__ u32   swi[4][16];
    const int bid = blockIdx.x;
    if (bid >= 2048) {
        cvt_chunk<256, 16>(1536 + (bid - 2048), threadIdx.x, down, up, downb, upb);
        return;
    }
    const int w = threadIdx.x >> 6;
    const int lane = threadIdx.x & 63;
    const int row = bid * 4 + w;
    const u64 below = (1ULL << lane) - 1;

    // ---- Stage A: per-half top-16 set (both halves interleaved for ILP) ----
    float v0[2], v1[2];
    u32 o0[2], o1[2], cur[2];
    v0[0] = s0[(size_t)row * 128 + lane];
    v1[0] = s0[(size_t)row * 128 + 64 + lane];
    v0[1] = s1[(size_t)row * 128 + lane];
    v1[1] = s1[(size_t)row * 128 + 64 + lane];
#pragma unroll
    for (int h = 0; h < 2; h++) {
        o0[h] = ordf(v0[h]); o1[h] = ordf(v1[h]); cur[h] = 0u;
    }
    for (int bit = 31; bit >= 0; --bit) {
#pragma unroll
        for (int h = 0; h < 2; h++) {
            u32 cand = cur[h] | (1u << bit);
            int c = __popcll(__ballot(o0[h] >= cand)) + __popcll(__ballot(o1[h] >= cand));
            if (c >= 16) cur[h] = cand;
        }
    }
#pragma unroll
    for (int h = 0; h < 2; h++) {
        u64 g0 = __ballot(o0[h] > cur[h]);
        u64 g1 = __ballot(o1[h] > cur[h]);
        const int cg0 = __popcll(g0);
        const int cntGT = cg0 + __popcll(g1);
        const int need = 16 - cntGT;             // >= 1 guaranteed
        u64 e0 = __ballot(o0[h] == cur[h]);
        u64 e1 = __ballot(o1[h] == cur[h]);
        const int ce0 = __popcll(e0);
        if (o0[h] > cur[h]) {
            int sl = __popcll(g0 & below);
            shv[w][h][sl] = v0[h]; shi[w][h][sl] = lane;
        }
        if (o1[h] > cur[h]) {
            int sl = cg0 + __popcll(g1 & below);
            shv[w][h][sl] = v1[h]; shi[w][h][sl] = lane + 64;
        }
        if (o0[h] == cur[h]) {
            int r = __popcll(e0 & below);
            if (r < need) { shv[w][h][cntGT + r] = v0[h]; shi[w][h][cntGT + r] = lane; }
        }
        if (o1[h] == cur[h]) {
            int r = ce0 + __popcll(e1 & below);
            if (r < need) { shv[w][h][cntGT + r] = v1[h]; shi[w][h][cntGT + r] = lane + 64; }
        }
    }

    // ---- Stage B: 256 cartesian candidates, exact top-16 ----
    float cv[4]; u32 ci[4], co[4];
#pragma unroll
    for (int qq = 0; qq < 4; qq++) {
        int id = lane + 64 * qq;
        int a = id >> 4, b = id & 15;
        cv[qq] = shv[w][0][a] + shv[w][1][b];
        ci[qq] = (u32)(shi[w][0][a] * 128 + shi[w][1][b]);
        co[qq] = ordf(cv[qq]);
    }
    u32 curV = 0;
    for (int bit = 31; bit >= 0; --bit) {
        u32 cand = curV | (1u << bit);
        int c = 0;
#pragma unroll
        for (int qq = 0; qq < 4; qq++) c += __popcll(__ballot(co[qq] >= cand));
        if (c >= 16) curV = cand;
    }
    bool gtf[4], eqf[4];
    int cntGT = 0;
#pragma unroll
    for (int qq = 0; qq < 4; qq++) {
        gtf[qq] = (co[qq] > curV);
        eqf[qq] = (co[qq] == curV);
        cntGT += __popcll(__ballot(gtf[qq]));
    }
    const int need = 16 - cntGT;                 // >= 1 guaranteed
    // minimal I with count(eq && idx <= I) >= need (flat idx unique)
    u32 I = 0;
    for (int bit = 13; bit >= 0; --bit) {
        u32 cand = I | ((1u << bit) - 1u);       // bit=0, lower bits=1
        int c = 0;
#pragma unroll
        for (int qq = 0; qq < 4; qq++)
            c += __popcll(__ballot(eqf[qq] && (ci[qq] <= cand)));
        if (c < need) I |= (1u << bit);
    }
    // selection + compaction (exactly 16)
    int pre = 0;
#pragma unroll
    for (int qq = 0; qq < 4; qq++) {
        bool sel = gtf[qq] || (eqf[qq] && (ci[qq] <= I));
        u64 sm = __ballot(sel);
        if (sel) {
            int sl = pre + __popcll(sm & below);
            swv[w][sl] = cv[qq]; swi[w][sl] = ci[qq];
        }
        pre += __popcll(sm);
    }

    // ---- exact sort of 16 + softmax ----
    if (lane < 16) {
        float myv = swv[w][lane];
        u32 myi = swi[w][lane];
        u64 myk = mkkey2(myv, myi);
        int rank = 0;
#pragma unroll
        for (int j = 0; j < 16; j++) {
            u64 kj = mkkey2(swv[w][j], swi[w][j]);
            rank += (kj > myk);
        }
        float vmax = myv;
#pragma unroll
        for (int off = 1; off < 16; off <<= 1)
            vmax = fmaxf(vmax, __shfl_xor(vmax, off, 16));
        float e = expf(myv - vmax);
        float ssum = e;
#pragma unroll
        for (int off = 1; off < 16; off <<= 1) ssum += __shfl_xor(ssum, off, 16);
        tW[(size_t)row * 16 + rank] = e / ssum;
        tIdx[(size_t)row * 16 + rank] = (int)myi;
    }
}

// ---------------------------------------------------------------------------
// K5 merged (bf16), occupancy-split: grid = token x expert-half, 512 thr.
// Phase 1: 64 coefs (8 waves x 8 experts, math identical per expert).
// Phase 2: 4 groups of 16 experts, uint4 gathers, 3x1024 LDS partials,
// then atomicAdd into out (exactly 2 contributions/element -> deterministic).
// ---------------------------------------------------------------------------
__global__ __launch_bounds__(512) void k_mlp_bf(const float* __restrict__ hidden,
                                                const ushort_t* __restrict__ downb,
                                                const ushort_t* __restrict__ upb,
                                                const int* __restrict__ tIdx,
                                                const float* __restrict__ tW,
                                                float* __restrict__ out)
{
    __shared__ float cf[64];
    __shared__ int   ei[64];
    __shared__ float part[3 * 1024];
    const int t = blockIdx.x >> 1;
    const int hh = blockIdx.x & 1;       // expert half
    const int pbase = hh * 64;
    const int tid = threadIdx.x;         // 0..511
    const int wave = tid >> 6, lane = tid & 63;

    if (tid < 64) ei[tid] = tIdx[(size_t)t * 128 + pbase + tid];

    const float* hp = hidden + (size_t)t * 1024;
    float h[16];
    *(float4*)(h + 0)  = *(const float4*)(hp + lane * 8);
    *(float4*)(h + 4)  = *(const float4*)(hp + lane * 8 + 4);
    *(float4*)(h + 8)  = *(const float4*)(hp + 512 + lane * 8);
    *(float4*)(h + 12) = *(const float4*)(hp + 512 + lane * 8 + 4);

    // ---- phase 1: 64 coefs into LDS (8 waves x 2 groups of 4 experts) ----
#pragma unroll
    for (int g = 0; g < 2; g++) {
        const int pg = wave * 8 + g * 4;         // local expert base 0..60
        float s[4];
        uint4 a[4], b[4];
#pragma unroll
        for (int i = 0; i < 4; i++) {
            const int e = tIdx[(size_t)t * 128 + pbase + pg + i];
            const uint4* rp = (const uint4*)(downb + (size_t)e * 1024);
            a[i] = rp[lane];
            b[i] = rp[lane + 64];
        }
#pragma unroll
        for (int i = 0; i < 4; i++) {
            float acc = 0.f;
            const u32* aw = (const u32*)&a[i];
            const u32* bw = (const u32*)&b[i];
#pragma unroll
            for (int c = 0; c < 4; c++) {
                acc = fmaf(bf_lo(aw[c]), h[2 * c], acc);
                acc = fmaf(bf_hi(aw[c]), h[2 * c + 1], acc);
                acc = fmaf(bf_lo(bw[c]), h[8 + 2 * c], acc);
                acc = fmaf(bf_hi(bw[c]), h[8 + 2 * c + 1], acc);
            }
            s[i] = acc;
        }
#pragma unroll
        for (int i = 0; i < 4; i++)
#pragma unroll
            for (int off = 1; off < 64; off <<= 1) s[i] += __shfl_xor(s[i], off);
        if (lane < 4) {
            float x = (lane == 0) ? s[0] : (lane == 1) ? s[1] : (lane == 2) ? s[2] : s[3];
            float wv = tW[(size_t)t * 128 + pbase + pg + lane];
            float gl = 0.5f * x * (1.0f + erff(x * 0.70710678118654752f));
            cf[pg + lane] = wv * gl;
        }
    }
    __syncthreads();   // cf[], ei[] ready

    // ---- phase 2: 4 groups of 16 experts, uint4 gathers ----
    const int g4 = tid >> 7;             // 0..3 -> local experts [g4*16, +16)
    const int jl = (tid & 127) * 8;      // 8 columns per thread
    float acc[8] = {};
    const int p0 = g4 * 16;
#pragma unroll 4
    for (int p = p0; p < p0 + 16; p++) {
        const float c = cf[p];
        uint4 v = *(const uint4*)(upb + (size_t)ei[p] * 1024 + jl);
        acc[0] = fmaf(c, bf_lo(v.x), acc[0]);
        acc[1] = fmaf(c, bf_hi(v.x), acc[1]);
        acc[2] = fmaf(c, bf_lo(v.y), acc[2]);
        acc[3] = fmaf(c, bf_hi(v.y), acc[3]);
        acc[4] = fmaf(c, bf_lo(v.z), acc[4]);
        acc[5] = fmaf(c, bf_hi(v.z), acc[5]);
        acc[6] = fmaf(c, bf_lo(v.w), acc[6]);
        acc[7] = fmaf(c, bf_hi(v.w), acc[7]);
    }
    if (g4) {
        *(float4*)&part[(g4 - 1) * 1024 + jl]     = *(float4*)(acc);
        *(float4*)&part[(g4 - 1) * 1024 + jl + 4] = *(float4*)(acc + 4);
    }
    __syncthreads();
    if (g4 == 0) {
        float r[8];
        *(float4*)(r)     = *(float4*)(acc);
        *(float4*)(r + 4) = *(float4*)(acc + 4);
#pragma unroll
        for (int p = 0; p < 3; p++) {
            float4 a0 = *(float4*)&part[p * 1024 + jl];
            float4 a1 = *(float4*)&part[p * 1024 + jl + 4];
            r[0] += a0.x; r[1] += a0.y; r[2] += a0.z; r[3] += a0.w;
            r[4] += a1.x; r[5] += a1.y; r[6] += a1.z; r[7] += a1.w;
        }
        float* op = out + (size_t)t * 1024 + jl;
#pragma unroll
        for (int k2 = 0; k2 < 8; k2++)
            atomicAdd(op + k2, r[k2]);
    }
}

// K5a fallback (fp32 tables)
__global__ __launch_bounds__(1024) void k_coef_f32(const float* __restrict__ hidden,
                                                   const float* __restrict__ down,
                                                   const int* __restrict__ tIdx,
                                                   const float* __restrict__ tW,
                                                   float* __restrict__ coef)
{
    __shared__ __align__(16) float hs[1024];
    __shared__ int   eidx[128];
    __shared__ float wv[128];
    const int t = blockIdx.x;
    const int tid = threadIdx.x;
    hs[tid] = hidden[(size_t)t * 1024 + tid];
    if (tid < 128) {
        eidx[tid] = tIdx[(size_t)t * 128 + tid];
        wv[tid]   = tW[(size_t)t * 128 + tid];
    }
    __syncthreads();
    const int wave = tid >> 6, lane = tid & 63;
#pragma unroll 2
    for (int i = 0; i < 8; i++) {
        const int p = wave * 8 + i;
        const float4* dp = (const float4*)(down + (size_t)eidx[p] * 1024);
        float sum = 0.f;
#pragma unroll
        for (int c = 0; c < 4; c++) {
            float4 dv = dp[lane + 64 * c];
            float4 hv = *(const float4*)(hs + (lane + 64 * c) * 4);
            sum += dv.x * hv.x + dv.y * hv.y + dv.z * hv.z + dv.w * hv.w;
        }
        for (int off = 32; off; off >>= 1) sum += __shfl_down(sum, off);
        if (lane == 0) {
            float x = sum;
            float g = 0.5f * x * (1.0f + erff(x * 0.70710678118654752f));
            coef[(size_t)t * 128 + p] = wv[p] * g;
        }
    }
}

// K5b fallback (fp32 tables)
__global__ __launch_bounds__(256) void k_accum_f32(const float* __restrict__ up,
                                                   const int* __restrict__ tIdx,
                                                   const float* __restrict__ coef,
                                                   float* __restrict__ out)
{
    __shared__ float cf[128];
    __shared__ int   ei[128];
    const int t = blockIdx.x >> 2;
    const int c = blockIdx.x & 3;
    const int tid = threadIdx.x;
    if (tid < 128) {
        cf[tid] = coef[(size_t)t * 128 + tid];
        ei[tid] = tIdx[(size_t)t * 128 + tid];
    }
    __syncthreads();
    const int j = c * 256 + tid;
    float acc = 0.f;
#pragma unroll 8
    for (int p = 0; p < 128; p++)
        acc = fmaf(cf[p], up[(size_t)ei[p] * 1024 + j], acc);
    out[(size_t)t * 1024 + j] = acc;
}

// ---------------------------------------------------------------------------
// Fallback fused launch (fp32 qproj 64x64 full-K + keynorm) — ws too small.
// ---------------------------------------------------------------------------
__global__ __launch_bounds__(256) void k_fall1(
    const float* __restrict__ A, const float* __restrict__ W,
    float* __restrict__ qp,
    const float* __restrict__ sk0, const float* __restrict__ sk1,
    float* __restrict__ k0n, float* __restrict__ k1n)
{
    __shared__ float smem[2 * 32 * 68];
    const int bid = blockIdx.x;
    const int tid = threadIdx.x;

    if (bid < 512) {
        float* As = smem;
        float* Bs = smem + 32 * 68;
        const int m0 = (bid >> 5) * 64;
        const int n0 = (bid & 31) * 64;
        const int aM  = tid >> 3;
        const int aK4 = (tid & 7) * 4;
        const int bK  = tid >> 4;
        const int bN4 = (tid & 15) * 4;
        const int ty  = tid >> 4;
        const int tx  = tid & 15;
        float acc[4][4] = {};
        for (int kk = 0; kk < 1024; kk += 32) {
            __syncthreads();
#pragma unroll
            for (int p = 0; p < 2; p++) {
                int m = aM + 32 * p;
                float4 v = *(const float4*)(A + (size_t)(m0 + m) * DDIM + kk + aK4);
                As[(aK4 + 0) * 68 + m] = v.x; As[(aK4 + 1) * 68 + m] = v.y;
                As[(aK4 + 2) * 68 + m] = v.z; As[(aK4 + 3) * 68 + m] = v.w;
            }
#pragma unroll
            for (int p = 0; p < 2; p++) {
                int k = bK + 16 * p;
                float4 v = *(const float4*)(W + (size_t)(kk + k) * HQD + n0 + bN4);
                *(float4*)&Bs[k * 68 + bN4] = v;
            }
            __syncthreads();
#pragma unroll
            for (int k = 0; k < 32; k++) {
                float a[4], b[4];
                *(float4*)(a) = *(const float4*)&As[k * 68 + ty * 4];
                *(float4*)(b) = *(const float4*)&Bs[k * 68 + tx * 4];
#pragma unroll
                for (int i = 0; i < 4; i++)
#pragma unroll
                    for (int j = 0; j < 4; j++)
                        acc[i][j] = fmaf(a[i], b[j], acc[i][j]);
            }
        }
#pragma unroll
        for (int i = 0; i < 4; i++) {
            int m = m0 + ty * 4 + i;
            float4 r;
            r.x = acc[i][0]; r.y = acc[i][1]; r.z = acc[i][2]; r.w = acc[i][3];
            *(float4*)(qp + (size_t)m * HQD + n0 + tx * 4) = r;
        }
    } else {
        const int b2 = bid - 512;
        const int sub = tid >> 7;
        const int col = tid & 127;
        const int gr = b2 * 2 + sub;
        const float* src = (gr < 128) ? sk0 : sk1;
        float* dst = (gr < 128) ? k0n : k1n;
        const int row = gr & 127;
        float v = src[row * 128 + col];
        float sq = v * v;
        for (int off = 32; off; off >>= 1) sq += __shfl_down(sq, off);
        if ((tid & 63) == 0) smem[tid >> 6] = sq;
        __syncthreads();
        if ((tid & 127) == 0) {
            float n = sqrtf(smem[tid >> 6] + smem[(tid >> 6) + 1]);
            smem[8 + sub] = 1.0f / fmaxf(n, 1e-12f);
        }
        __syncthreads();
        dst[row * 128 + col] = v * smem[8 + sub];
    }
}

// ---------------------------------------------------------------------------
extern "C" void kernel_launch(void* const* d_in, const int* in_sizes, int n_in,
                              void* d_out, int out_size, void* d_ws, size_t ws_size,
                              hipStream_t stream)
{
    const float* hidden = (const float*)d_in[0];
    const float* Wq     = (const float*)d_in[1];
    const float* bq     = (const float*)d_in[2];
    const float* gamma  = (const float*)d_in[3];
    const float* beta   = (const float*)d_in[4];
    const float* sk0    = (const float*)d_in[5];
    const float* sk1    = (const float*)d_in[6];
    const float* down   = (const float*)d_in[7];
    const float* up     = (const float*)d_in[8];
    float* out = (float*)d_out;

    float* ws = (float*)d_ws;
    size_t o = 0;
    float* qp    = ws + o; o += (size_t)TOKENS * HQD;      // 2M floats
    float* ps    = ws + o; o += 512 * 256;
    float* pq    = ws + o; o += 512 * 256;
    float* meanb = ws + o; o += 256;
    float* scaleb= ws + o; o += 256;
    float* k0n   = ws + o; o += NKEY * 128;
    float* k1n   = ws + o; o += NKEY * 128;
    float* s0    = ws + o; o += (size_t)NROWS * 128;
    float* s1    = ws + o; o += (size_t)NROWS * 128;
    float* tW    = ws + o; o += (size_t)NROWS * TOPK;
    int*   tIdx  = (int*)(ws + o); o += (size_t)NROWS * TOPK;
    float* coef  = ws + o; o += (size_t)TOKENS * 128;
    ushort_t* downb = (ushort_t*)(ws + o); o += (size_t)16384 * 1024 / 2;
    ushort_t* upb   = (ushort_t*)(ws + o); o += (size_t)16384 * 1024 / 2;
    ushort_t* Ab    = (ushort_t*)(ws + o); o += (size_t)1024 * 2048 / 2;   // 1M floats
    ushort_t* Wt    = (ushort_t*)(ws + o); o += (size_t)2048 * 2048 / 2;   // 2M floats
    const int useBF = (ws_size >= o * sizeof(float)) ? 1 : 0;
    const float qsc = useBF ? QINVS : 1.0f;

    if (useBF) {
        hipMemsetAsync(out, 0, (size_t)out_size * sizeof(float), stream);
        k_prep1 <<<768, 256, 0, stream>>>(hidden, Wq, Ab, Wt, sk0, sk1, k0n, k1n);
        k_fused2<<<1536, 256, 0, stream>>>(Ab, Wt, qp, down, up, downb, upb);
        k_bnstat1<<<512, 256, 0, stream>>>(qp, bq, ps, pq, qsc);
        k_bnstat2<<<8, 256, 0, stream>>>(ps, pq, gamma, meanb, scaleb);
        k_scores <<<768, 256, 0, stream>>>(qp, bq, meanb, scaleb, beta,
                                           k0n, k1n, s0, s1, qsc,
                                           down, up, downb, upb);
        k_topk   <<<2560, 256, 0, stream>>>(s0, s1, tIdx, tW, down, up, downb, upb);
        k_mlp_bf <<<2 * TOKENS, 512, 0, stream>>>(hidden, downb, upb, tIdx, tW, out);
    } else {
        k_fall1 <<<640, 256, 0, stream>>>(hidden, Wq, qp, sk0, sk1, k0n, k1n);
        k_bnstat1<<<512, 256, 0, stream>>>(qp, bq, ps, pq, qsc);
        k_bnstat2<<<8, 256, 0, stream>>>(ps, pq, gamma, meanb, scaleb);
        k_scores <<<256, 256, 0, stream>>>(qp, bq, meanb, scaleb, beta,
                                           k0n, k1n, s0, s1, qsc,
                                           down, up, downb, upb);
        k_topk   <<<2048, 256, 0, stream>>>(s0, s1, tIdx, tW, down, up, downb, upb);
        k_coef_f32 <<<TOKENS, 1024, 0, stream>>>(hidden, down, tIdx, tW, coef);
        k_accum_f32<<<4096, 256, 0, stream>>>(up, tIdx, coef, out);
    }
}

// Round 16
// 182.781 us; speedup vs baseline: 1.1775x; 1.1775x over previous
//
#include <hip/hip_runtime.h>
#include <math.h>

typedef unsigned long long u64;
typedef unsigned int u32;
typedef unsigned short ushort_t;
typedef _Float16 half8 __attribute__((ext_vector_type(8)));
typedef float f32x4 __attribute__((ext_vector_type(4)));

// Problem constants
#define TOKENS 1024   // B*S = 2*512
#define DDIM   1024
#define NHEAD  8
#define QD     256
#define HQD    2048   // NHEAD*QD
#define NROWS  8192   // TOKENS*NHEAD
#define NKEY   128
#define TOPK   16

#define QSCALE 256.0f            // pre-scale for A and W before f16 split
#define QINVS  (1.0f / 65536.0f) // 1/(256*256), exact

__device__ __forceinline__ ushort_t f2bf(float f) {
    u32 u = __float_as_uint(f);
    u32 r = (u + 0x7FFFu + ((u >> 16) & 1u)) >> 16;   // RNE
    return (ushort_t)r;
}
__device__ __forceinline__ float bf_lo(u32 w) { return __uint_as_float(w << 16); }
__device__ __forceinline__ float bf_hi(u32 w) { return __uint_as_float(w & 0xFFFF0000u); }

// f16 2-term split: x = h + l + O(2^-24 x)
__device__ __forceinline__ void hsplit(float x, ushort_t& h, ushort_t& l) {
    _Float16 hh = (_Float16)x;          // RNE
    float r = x - (float)hh;            // exact
    _Float16 ll = (_Float16)r;
    union { _Float16 f; ushort_t u; } c1, c2;
    c1.f = hh; c2.f = ll;
    h = c1.u; l = c2.u;
}

// orderable u32 from float: larger code <=> larger float
__device__ __forceinline__ u32 ordf(float v) {
    u32 u = __float_as_uint(v);
    return (u & 0x80000000u) ? ~u : (u | 0x80000000u);
}
__device__ __forceinline__ u64 mkkey2(float v, u32 idx) {
    return ((u64)ordf(v) << 32) | (u64)(0xFFFFFFFFu - idx);
}

// One cvt work-unit = 16384 elems (gcb in [0,2048): <1024 = down, else up).
template<int NTHR, int ITERS>
__device__ __forceinline__ void cvt_chunk(int gcb, int tid,
                                          const float* __restrict__ down,
                                          const float* __restrict__ up,
                                          ushort_t* __restrict__ downb,
                                          ushort_t* __restrict__ upb) {
    const float* src = (gcb < 1024) ? down : up;
    ushort_t* dst = (gcb < 1024) ? downb : upb;
    const size_t base4 = (size_t)(gcb & 1023) * 4096;
    const float4* s4 = (const float4*)src;
    ushort4* d4 = (ushort4*)dst;
#pragma unroll 4
    for (int it = 0; it < ITERS; it++) {
        size_t i = base4 + (size_t)it * NTHR + tid;
        float4 v = s4[i];
        ushort4 o;
        o.x = f2bf(v.x); o.y = f2bf(v.y); o.z = f2bf(v.z); o.w = f2bf(v.w);
        d4[i] = o;
    }
}

// ---------------------------------------------------------------------------
// k_prep1 (256 thr):
//   [0,128):   A*256 -> f16 hi|lo  Ab[m][0:1024]=hi, [1024:2048]=lo
//   [128,640): W*256 -> transpose + f16 hi|lo  Wt[n][0:1024]=hi(k), [1024:]=lo
//   [640,768): sub_key L2-normalize (2 rows/block)
// ---------------------------------------------------------------------------
__global__ __launch_bounds__(256) void k_prep1(
    const float* __restrict__ A, const float* __restrict__ W,
    ushort_t* __restrict__ Ab, ushort_t* __restrict__ Wt,
    const float* __restrict__ sk0, const float* __restrict__ sk1,
    float* __restrict__ k0n, float* __restrict__ k1n)
{
    __shared__ __align__(16) char praw[18464];
    const int bid = blockIdx.x;
    const int tid = threadIdx.x;

    if (bid < 128) {
        // ---------------- A -> hi|lo ----------------
#pragma unroll
        for (int i = 0; i < 8; i++) {
            const int row = bid * 8 + i;
            float4 v = *(const float4*)(A + (size_t)row * 1024 + tid * 4);
            ushort4 h, l;
            hsplit(v.x * QSCALE, h.x, l.x);
            hsplit(v.y * QSCALE, h.y, l.y);
            hsplit(v.z * QSCALE, h.z, l.z);
            hsplit(v.w * QSCALE, h.w, l.w);
            *(ushort4*)(Ab + (size_t)row * 2048 + tid * 4) = h;
            *(ushort4*)(Ab + (size_t)row * 2048 + 1024 + tid * 4) = l;
        }
    } else if (bid < 640) {
        // ---------------- W transpose + hi|lo (64k x 64n tile) ----------------
        const int cb = bid - 128;                  // 0..511
        const int k0 = (cb >> 5) * 64;
        const int n0 = (cb & 31) * 64;
        ushort_t* Lh = (ushort_t*)praw;            // [64n][72]
        ushort_t* Ll = (ushort_t*)praw + 4608;
        const int nn = (tid & 15) * 4;
        const int kk = tid >> 4;                   // 0..15
#pragma unroll
        for (int p = 0; p < 4; p++) {
            const int k = kk + 16 * p;
            float4 v = *(const float4*)(W + (size_t)(k0 + k) * HQD + n0 + nn);
            float xs[4] = {v.x * QSCALE, v.y * QSCALE, v.z * QSCALE, v.w * QSCALE};
#pragma unroll
            for (int j = 0; j < 4; j++) {
                ushort_t h, l;
                hsplit(xs[j], h, l);
                Lh[(nn + j) * 72 + k] = h;
                Ll[(nn + j) * 72 + k] = l;
            }
        }
        __syncthreads();
#pragma unroll
        for (int e = 0; e < 2; e++) {
            const int idx = tid + 256 * e;
            const int n = idx >> 3, ks = idx & 7;
            uint4 hv = *(const uint4*)(Lh + n * 72 + ks * 8);
            uint4 lv = *(const uint4*)(Ll + n * 72 + ks * 8);
            *(uint4*)(Wt + (size_t)(n0 + n) * 2048 + k0 + ks * 8) = hv;
            *(uint4*)(Wt + (size_t)(n0 + n) * 2048 + 1024 + k0 + ks * 8) = lv;
        }
    } else {
        // ---------------- key L2-normalize (2 rows/block) ----------------
        float* fs = (float*)praw;
        const int b2 = bid - 640;                  // 0..127
        const int sub = tid >> 7;
        const int col = tid & 127;
        const int gr = b2 * 2 + sub;
        const float* src = (gr < 128) ? sk0 : sk1;
        float* dst = (gr < 128) ? k0n : k1n;
        const int row = gr & 127;
        float v = src[row * 128 + col];
        float sq = v * v;
        for (int off = 32; off; off >>= 1) sq += __shfl_down(sq, off);
        if ((tid & 63) == 0) fs[tid >> 6] = sq;
        __syncthreads();
        if ((tid & 127) == 0) {
            float n = sqrtf(fs[tid >> 6] + fs[(tid >> 6) + 1]);
            fs[8 + sub] = 1.0f / fmaxf(n, 1e-12f);
        }
        __syncthreads();
        dst[row * 128 + col] = v * fs[8 + sub];
    }
}

// ---------------------------------------------------------------------------
// k_fused2:
//   blocks [0,512):     qmfma 64x64 full-K f16 MFMA 3-term (verified body)
//   blocks [512,1536):  down-cvt gcb [0,1024)  (overlaps GEMM's idle HBM)
// ---------------------------------------------------------------------------
__global__ __launch_bounds__(256) void k_fused2(
    const ushort_t* __restrict__ Ab, const ushort_t* __restrict__ Wt,
    float* __restrict__ qp,
    const float* __restrict__ down, const float* __restrict__ up,
    ushort_t* __restrict__ downb, ushort_t* __restrict__ upb)
{
    __shared__ __align__(16) char lds[2][16384];   // per buf: As 8K + Bs 8K
    const int tid = threadIdx.x;
    const int bid = blockIdx.x;

    if (bid >= 512) {
        cvt_chunk<256, 16>(bid - 512, tid, down, up, downb, upb);
        return;
    }

    const int m0 = (bid >> 5) * 64;      // 16 m-tiles
    const int n0 = (bid & 31) * 64;      // 32 n-tiles

    const int srow = tid >> 2;           // 0..63 staging row
    const int scol = (tid & 3) * 16;     // ushort offset (32B chunk)
    const int swz = (srow & 7) << 4;

    const int lane = tid & 63;
    const int w = tid >> 6;
    const int wmb = (w >> 1) * 32;
    const int wnb = (w & 1) * 32;
    const int fr = lane & 15;
    const int kg = lane >> 4;
    const int rswz = (fr & 7) << 4;

    f32x4 acc[2][2];
#pragma unroll
    for (int i = 0; i < 2; i++)
#pragma unroll
        for (int j = 0; j < 2; j++)
            acc[i][j] = (f32x4){0.f, 0.f, 0.f, 0.f};

    uint4 ar0, ar1, br0, br1;

    auto LOADR = [&](int gs) {
        const int term = gs >> 4;                   // 0:HH 1:LH 2:HL
        const int aoff = (term == 1) ? 1024 : 0;
        const int woff = (term == 2) ? 1024 : 0;
        const int kb = (gs & 15) * 64;
        const ushort_t* ap = Ab + (size_t)(m0 + srow) * 2048 + aoff + kb + scol;
        const ushort_t* wp = Wt + (size_t)(n0 + srow) * 2048 + woff + kb + scol;
        ar0 = *(const uint4*)(ap);
        ar1 = *(const uint4*)(ap + 8);
        br0 = *(const uint4*)(wp);
        br1 = *(const uint4*)(wp + 8);
    };
    auto WLDS = [&](int buf) {
        char* As = lds[buf];
        char* Bs = lds[buf] + 8192;
        const int b0 = (srow * 128 + scol * 2) ^ swz;
        const int b1 = (srow * 128 + scol * 2 + 16) ^ swz;
        *(uint4*)(As + b0) = ar0;
        *(uint4*)(As + b1) = ar1;
        *(uint4*)(Bs + b0) = br0;
        *(uint4*)(Bs + b1) = br1;
    };

    LOADR(0);
    WLDS(0);

    for (int s = 0; s < 48; s++) {
        __syncthreads();                     // buf[s&1] writes visible
        if (s < 47) LOADR(s + 1);            // prefetch next into regs
        const char* As = lds[s & 1];
        const char* Bs = lds[s & 1] + 8192;
#pragma unroll
        for (int kh = 0; kh < 2; kh++) {
            half8 a[2], b[2];
#pragma unroll
            for (int f = 0; f < 2; f++) {
                const int rowA = wmb + f * 16 + fr;
                a[f] = *(const half8*)(As + ((rowA * 128 + kh * 64 + kg * 16) ^ rswz));
                const int rowB = wnb + f * 16 + fr;
                b[f] = *(const half8*)(Bs + ((rowB * 128 + kh * 64 + kg * 16) ^ rswz));
            }
#pragma unroll
            for (int fm = 0; fm < 2; fm++)
#pragma unroll
                for (int fn = 0; fn < 2; fn++)
                    acc[fm][fn] = __builtin_amdgcn_mfma_f32_16x16x32_f16(
                        a[fm], b[fn], acc[fm][fn], 0, 0, 0);
        }
        if (s < 47) WLDS((s + 1) & 1);       // write NEXT buffer (no race)
    }

#pragma unroll
    for (int fm = 0; fm < 2; fm++) {
        const int rbase = m0 + wmb + fm * 16 + kg * 4;
#pragma unroll
        for (int fn = 0; fn < 2; fn++) {
            const int c = n0 + wnb + fn * 16 + fr;
#pragma unroll
            for (int j = 0; j < 4; j++)
                qp[(size_t)(rbase + j) * HQD + c] = acc[fm][fn][j];
        }
    }
}

// ---------------------------------------------------------------------------
// K2a: stats-only column sums/sumsq of (qsc*qp+bias)  [8192][256]
// ---------------------------------------------------------------------------
__global__ __launch_bounds__(256) void k_bnstat1(const float* __restrict__ qp,
                                                 const float* __restrict__ bq,
                                                 float* __restrict__ psum,
                                                 float* __restrict__ psq,
                                                 float qsc)
{
    const int b = blockIdx.x;
    const int j = threadIdx.x;
    float s = 0.f, sq = 0.f;
#pragma unroll 4
    for (int rr = 0; rr < 16; rr++) {
        const int r = b * 16 + rr;
        const size_t g = (size_t)r * 256 + j;
        float v = qp[g] * qsc + bq[(r & 7) * 256 + j];
        s += v; sq += v * v;
    }
    psum[b * 256 + j] = s;
    psq[b * 256 + j]  = sq;
}

// K2b: finish stats -> mean[j], scale[j] = gamma/sqrt(var+eps)
// 8 blocks x 256 thr
__global__ __launch_bounds__(256) void k_bnstat2(const float* __restrict__ psum,
                                                 const float* __restrict__ psq,
                                                 const float* __restrict__ gamma,
                                                 float* __restrict__ meanOut,
                                                 float* __restrict__ scaleOut)
{
    __shared__ float ls[8][64];   // [seg][2*32]
    const int col = blockIdx.x * 32 + (threadIdx.x & 31);
    const int seg = threadIdx.x >> 5;
    float s = 0.f, sq = 0.f;
    for (int b = seg; b < 512; b += 8) {
        s += psum[b * 256 + col];
        sq += psq[b * 256 + col];
    }
    ls[seg][(threadIdx.x & 31)] = s;
    ls[seg][32 + (threadIdx.x & 31)] = sq;
    __syncthreads();
    if (threadIdx.x < 32) {
        float ts = 0.f, tq = 0.f;
#pragma unroll
        for (int g = 0; g < 8; g++) {
            ts += ls[g][threadIdx.x];
            tq += ls[g][32 + threadIdx.x];
        }
        float mean = ts * (1.0f / 8192.0f);
        float var = tq * (1.0f / 8192.0f) - mean * mean;
        meanOut[col] = mean;
        scaleOut[col] = gamma[col] / sqrtf(var + 1e-5f);
    }
}

// ---------------------------------------------------------------------------
// K4: fused BN + per-half L2-norm + scores. 1D grid:
//   blocks [0,256): scores (half = bid>>7, row0 = (bid&127)*64)
//   blocks [256,768): up-cvt gcb [1024,1536)
// ---------------------------------------------------------------------------
__global__ __launch_bounds__(256) void k_scores(const float* __restrict__ qp,
                                                const float* __restrict__ bq,
                                                const float* __restrict__ mean,
                                                const float* __restrict__ scale,
                                                const float* __restrict__ beta,
                                                const float* __restrict__ kn0,
                                                const float* __restrict__ kn1,
                                                float* __restrict__ sOut0,
                                                float* __restrict__ sOut1,
                                                float qsc,
                                                const float* __restrict__ down,
                                                const float* __restrict__ up,
                                                ushort_t* __restrict__ downb,
                                                ushort_t* __restrict__ upb)
{
    __shared__ float Qs[128 * 68];   // [d][r]
    __shared__ float Ks[64 * 132];   // [d][n]
    __shared__ float rp[4][64];
    __shared__ float invn[64];
    const int bid = blockIdx.x;
    const int tid = threadIdx.x;
    if (bid >= 256) {
        cvt_chunk<256, 16>(1024 + (bid - 256), tid, down, up, downb, upb);
        return;
    }
    const int half = bid >> 7;
    const int row0 = (bid & 127) * 64;

    // ---- stage BN-transformed Q (full 128-dim half-rows) ----
    {
        const int d4 = (tid & 31) * 4;       // 0..124
        const int rbase = tid >> 5;          // 0..7 (head index of its rows)
        const int j4 = half * 128 + d4;
        float4 m4 = *(const float4*)(mean + j4);
        float4 sc4 = *(const float4*)(scale + j4);
        float4 be4 = *(const float4*)(beta + j4);
        float4 bi4 = *(const float4*)(bq + rbase * 256 + j4);
#pragma unroll
        for (int p = 0; p < 8; p++) {
            const int rr = rbase + p * 8;
            const int row = row0 + rr;                  // (row&7)==rbase
            const size_t g = (size_t)(row >> 3) * 2048 + (size_t)rbase * 256 + j4;
            float4 a = *(const float4*)(qp + g);
            float x0 = (a.x * qsc + bi4.x - m4.x) * sc4.x + be4.x;
            float x1 = (a.y * qsc + bi4.y - m4.y) * sc4.y + be4.y;
            float x2 = (a.z * qsc + bi4.z - m4.z) * sc4.z + be4.z;
            float x3 = (a.w * qsc + bi4.w - m4.w) * sc4.w + be4.w;
            Qs[(d4 + 0) * 68 + rr] = x0;
            Qs[(d4 + 1) * 68 + rr] = x1;
            Qs[(d4 + 2) * 68 + rr] = x2;
            Qs[(d4 + 3) * 68 + rr] = x3;
        }
    }
    __syncthreads();
    // ---- per-row sumsq -> invnorm ----
    {
        const int r = tid & 63, qd = tid >> 6;
        float s = 0.f;
#pragma unroll 8
        for (int d = qd * 32; d < qd * 32 + 32; d++) {
            float v = Qs[d * 68 + r];
            s += v * v;
        }
        rp[qd][r] = s;
    }
    __syncthreads();
    if (tid < 64) {
        float s = rp[0][tid] + rp[1][tid] + rp[2][tid] + rp[3][tid];
        invn[tid] = 1.0f / fmaxf(sqrtf(s), 1e-12f);
    }

    const float* kn = half ? kn1 : kn0;
    float* sOut = half ? sOut1 : sOut0;
    const int ty = tid >> 5;   // 0..7  -> r = ty*8
    const int tx = tid & 31;   // 0..31 -> n = tx*4
    float acc[8][4] = {};

    for (int c = 0; c < 2; c++) {
        __syncthreads();
        {
            int dd4 = (tid & 15) * 4;
            int n = tid >> 4;  // 0..15
#pragma unroll
            for (int p = 0; p < 8; p++) {
                int nn = n + p * 16;
                float4 v = *(const float4*)(kn + nn * 128 + c * 64 + dd4);
                Ks[(dd4 + 0) * 132 + nn] = v.x; Ks[(dd4 + 1) * 132 + nn] = v.y;
                Ks[(dd4 + 2) * 132 + nn] = v.z; Ks[(dd4 + 3) * 132 + nn] = v.w;
            }
        }
        __syncthreads();
#pragma unroll
        for (int d = 0; d < 64; d++) {
            float a[8], b[4];
            *(float4*)(a)     = *(const float4*)&Qs[(c * 64 + d) * 68 + ty * 8];
            *(float4*)(a + 4) = *(const float4*)&Qs[(c * 64 + d) * 68 + ty * 8 + 4];
            *(float4*)(b)     = *(const float4*)&Ks[d * 132 + tx * 4];
#pragma unroll
            for (int i = 0; i < 8; i++)
#pragma unroll
                for (int j = 0; j < 4; j++)
                    acc[i][j] = fmaf(a[i], b[j], acc[i][j]);
        }
    }
#pragma unroll
    for (int i = 0; i < 8; i++) {
        const float iv = invn[ty * 8 + i];
        float4 r;
        r.x = acc[i][0] * iv; r.y = acc[i][1] * iv;
        r.z = acc[i][2] * iv; r.w = acc[i][3] * iv;
        *(float4*)(sOut + (size_t)(row0 + ty * 8 + i) * 128 + tx * 4) = r;
    }
}

// ---------------------------------------------------------------------------
// K4c: exact top-16 + softmax via ballot-radix threshold selection.
//   blocks [0,2048): topk (4 rows/block, one wave each)
//   blocks [2048,2560): up-cvt gcb [1536,2048)
// ---------------------------------------------------------------------------
__global__ __launch_bounds__(256) void k_topk(const float* __restrict__ s0,
                                              const float* __restrict__ s1,
                                              int* __restrict__ tIdx,
                                              float* __restrict__ tW,
                                              const float* __restrict__ down,
                                              const float* __restrict__ up,
                                              ushort_t* __restrict__ downb,
                                              ushort_t* __restrict__ upb)
{
    __shared__ float shv[4][2][16];
    __shared__ int   shi[4][2][16];
    __shared__ float swv[4][16];
    __shared__ u32   swi[4][16];
    const int bid = blockIdx.x;
    if (bid >= 2048) {
        cvt_chunk<256, 16>(1536 + (bid - 2048), threadIdx.x, down, up, downb, upb);
        return;
    }
    const int w = threadIdx.x >> 6;
    const int lane = threadIdx.x & 63;
    const int row = bid * 4 + w;
    const u64 below = (1ULL << lane) - 1;

    // ---- Stage A: per-half top-16 set (both halves interleaved for ILP) ----
    float v0[2], v1[2];
    u32 o0[2], o1[2], cur[2];
    v0[0] = s0[(size_t)row * 128 + lane];
    v1[0] = s0[(size_t)row * 128 + 64 + lane];
    v0[1] = s1[(size_t)row * 128 + lane];
    v1[1] = s1[(size_t)row * 128 + 64 + lane];
#pragma unroll
    for (int h = 0; h < 2; h++) {
        o0[h] = ordf(v0[h]); o1[h] = ordf(v1[h]); cur[h] = 0u;
    }
    for (int bit = 31; bit >= 0; --bit) {
#pragma unroll
        for (int h = 0; h < 2; h++) {
            u32 cand = cur[h] | (1u << bit);
            int c = __popcll(__ballot(o0[h] >= cand)) + __popcll(__ballot(o1[h] >= cand));
            if (c >= 16) cur[h] = cand;
        }
    }
#pragma unroll
    for (int h = 0; h < 2; h++) {
        u64 g0 = __ballot(o0[h] > cur[h]);
        u64 g1 = __ballot(o1[h] > cur[h]);
        const int cg0 = __popcll(g0);
        const int cntGT = cg0 + __popcll(g1);
        const int need = 16 - cntGT;             // >= 1 guaranteed
        u64 e0 = __ballot(o0[h] == cur[h]);
        u64 e1 = __ballot(o1[h] == cur[h]);
        const int ce0 = __popcll(e0);
        if (o0[h] > cur[h]) {
            int sl = __popcll(g0 & below);
            shv[w][h][sl] = v0[h]; shi[w][h][sl] = lane;
        }
        if (o1[h] > cur[h]) {
            int sl = cg0 + __popcll(g1 & below);
            shv[w][h][sl] = v1[h]; shi[w][h][sl] = lane + 64;
        }
        if (o0[h] == cur[h]) {
            int r = __popcll(e0 & below);
            if (r < need) { shv[w][h][cntGT + r] = v0[h]; shi[w][h][cntGT + r] = lane; }
        }
        if (o1[h] == cur[h]) {
            int r = ce0 + __popcll(e1 & below);
            if (r < need) { shv[w][h][cntGT + r] = v1[h]; shi[w][h][cntGT + r] = lane + 64; }
        }
    }

    // ---- Stage B: 256 cartesian candidates, exact top-16 ----
    float cv[4]; u32 ci[4], co[4];
#pragma unroll
    for (int qq = 0; qq < 4; qq++) {
        int id = lane + 64 * qq;
        int a = id >> 4, b = id & 15;
        cv[qq] = shv[w][0][a] + shv[w][1][b];
        ci[qq] = (u32)(shi[w][0][a] * 128 + shi[w][1][b]);
        co[qq] = ordf(cv[qq]);
    }
    u32 curV = 0;
    for (int bit = 31; bit >= 0; --bit) {
        u32 cand = curV | (1u << bit);
        int c = 0;
#pragma unroll
        for (int qq = 0; qq < 4; qq++) c += __popcll(__ballot(co[qq] >= cand));
        if (c >= 16) curV = cand;
    }
    bool gtf[4], eqf[4];
    int cntGT = 0;
#pragma unroll
    for (int qq = 0; qq < 4; qq++) {
        gtf[qq] = (co[qq] > curV);
        eqf[qq] = (co[qq] == curV);
        cntGT += __popcll(__ballot(gtf[qq]));
    }
    const int need = 16 - cntGT;                 // >= 1 guaranteed
    // minimal I with count(eq && idx <= I) >= need (flat idx unique)
    u32 I = 0;
    for (int bit = 13; bit >= 0; --bit) {
        u32 cand = I | ((1u << bit) - 1u);       // bit=0, lower bits=1
        int c = 0;
#pragma unroll
        for (int qq = 0; qq < 4; qq++)
            c += __popcll(__ballot(eqf[qq] && (ci[qq] <= cand)));
        if (c < need) I |= (1u << bit);
    }
    // selection + compaction (exactly 16)
    int pre = 0;
#pragma unroll
    for (int qq = 0; qq < 4; qq++) {
        bool sel = gtf[qq] || (eqf[qq] && (ci[qq] <= I));
        u64 sm = __ballot(sel);
        if (sel) {
            int sl = pre + __popcll(sm & below);
            swv[w][sl] = cv[qq]; swi[w][sl] = ci[qq];
        }
        pre += __popcll(sm);
    }

    // ---- exact sort of 16 + softmax ----
    if (lane < 16) {
        float myv = swv[w][lane];
        u32 myi = swi[w][lane];
        u64 myk = mkkey2(myv, myi);
        int rank = 0;
#pragma unroll
        for (int j = 0; j < 16; j++) {
            u64 kj = mkkey2(swv[w][j], swi[w][j]);
            rank += (kj > myk);
        }
        float vmax = myv;
#pragma unroll
        for (int off = 1; off < 16; off <<= 1)
            vmax = fmaxf(vmax, __shfl_xor(vmax, off, 16));
        float e = expf(myv - vmax);
        float ssum = e;
#pragma unroll
        for (int off = 1; off < 16; off <<= 1) ssum += __shfl_xor(ssum, off, 16);
        tW[(size_t)row * 16 + rank] = e / ssum;
        tIdx[(size_t)row * 16 + rank] = (int)myi;
    }
}

// ---------------------------------------------------------------------------
// K5 merged (bf16): per token, phase 1 computes coef[128] in LDS
// (w * gelu(down . hidden)), phase 2 does weighted up-row sum.
// Phase 2: 8-way expert split, uint4 (16B) gathers, 7x1024 LDS partials.
// ---------------------------------------------------------------------------
__global__ __launch_bounds__(1024) void k_mlp_bf(const float* __restrict__ hidden,
                                                 const ushort_t* __restrict__ downb,
                                                 const ushort_t* __restrict__ upb,
                                                 const int* __restrict__ tIdx,
                                                 const float* __restrict__ tW,
                                                 float* __restrict__ out)
{
    __shared__ float cf[128];
    __shared__ int   ei[128];
    __shared__ float part[7 * 1024];
    const int t = blockIdx.x;
    const int tid = threadIdx.x;
    const int wave = tid >> 6, lane = tid & 63;

    if (tid < 128) ei[tid] = tIdx[(size_t)t * 128 + tid];

    const float* hp = hidden + (size_t)t * 1024;
    float h[16];
    *(float4*)(h + 0)  = *(const float4*)(hp + lane * 8);
    *(float4*)(h + 4)  = *(const float4*)(hp + lane * 8 + 4);
    *(float4*)(h + 8)  = *(const float4*)(hp + 512 + lane * 8);
    *(float4*)(h + 12) = *(const float4*)(hp + 512 + lane * 8 + 4);

    // ---- phase 1: coef into LDS ----
#pragma unroll
    for (int g = 0; g < 2; g++) {
        const int pg = wave * 8 + g * 4;
        float s[4];
        uint4 a[4], b[4];
#pragma unroll
        for (int i = 0; i < 4; i++) {
            const int e = tIdx[(size_t)t * 128 + pg + i];
            const uint4* rp = (const uint4*)(downb + (size_t)e * 1024);
            a[i] = rp[lane];
            b[i] = rp[lane + 64];
        }
#pragma unroll
        for (int i = 0; i < 4; i++) {
            float acc = 0.f;
            const u32* aw = (const u32*)&a[i];
            const u32* bw = (const u32*)&b[i];
#pragma unroll
            for (int c = 0; c < 4; c++) {
                acc = fmaf(bf_lo(aw[c]), h[2 * c], acc);
                acc = fmaf(bf_hi(aw[c]), h[2 * c + 1], acc);
                acc = fmaf(bf_lo(bw[c]), h[8 + 2 * c], acc);
                acc = fmaf(bf_hi(bw[c]), h[8 + 2 * c + 1], acc);
            }
            s[i] = acc;
        }
#pragma unroll
        for (int i = 0; i < 4; i++)
#pragma unroll
            for (int off = 1; off < 64; off <<= 1) s[i] += __shfl_xor(s[i], off);
        if (lane < 4) {
            float x = (lane == 0) ? s[0] : (lane == 1) ? s[1] : (lane == 2) ? s[2] : s[3];
            float wv = tW[(size_t)t * 128 + pg + lane];
            float gl = 0.5f * x * (1.0f + erff(x * 0.70710678118654752f));
            cf[pg + lane] = wv * gl;
        }
    }
    __syncthreads();   // cf[], ei[] ready

    // ---- phase 2: weighted up-row sum, 8-way expert split, uint4 gathers ----
    const int g8 = tid >> 7;             // 0..7 -> experts [g8*16, g8*16+16)
    const int jl = (tid & 127) * 8;      // 8 columns per thread
    float acc[8] = {};
    const int p0 = g8 * 16;
#pragma unroll 4
    for (int p = p0; p < p0 + 16; p++) {
        const float c = cf[p];
        uint4 v = *(const uint4*)(upb + (size_t)ei[p] * 1024 + jl);
        acc[0] = fmaf(c, bf_lo(v.x), acc[0]);
        acc[1] = fmaf(c, bf_hi(v.x), acc[1]);
        acc[2] = fmaf(c, bf_lo(v.y), acc[2]);
        acc[3] = fmaf(c, bf_hi(v.y), acc[3]);
        acc[4] = fmaf(c, bf_lo(v.z), acc[4]);
        acc[5] = fmaf(c, bf_hi(v.z), acc[5]);
        acc[6] = fmaf(c, bf_lo(v.w), acc[6]);
        acc[7] = fmaf(c, bf_hi(v.w), acc[7]);
    }
    if (g8) {
        *(float4*)&part[(g8 - 1) * 1024 + jl]     = *(float4*)(acc);
        *(float4*)&part[(g8 - 1) * 1024 + jl + 4] = *(float4*)(acc + 4);
    }
    __syncthreads();
    if (g8 == 0) {
        float4 r0 = *(float4*)(acc);
        float4 r1 = *(float4*)(acc + 4);
#pragma unroll
        for (int p = 0; p < 7; p++) {
            float4 a0 = *(float4*)&part[p * 1024 + jl];
            float4 a1 = *(float4*)&part[p * 1024 + jl + 4];
            r0.x += a0.x; r0.y += a0.y; r0.z += a0.z; r0.w += a0.w;
            r1.x += a1.x; r1.y += a1.y; r1.z += a1.z; r1.w += a1.w;
        }
        *(float4*)(out + (size_t)t * 1024 + jl)     = r0;
        *(float4*)(out + (size_t)t * 1024 + jl + 4) = r1;
    }
}

// K5a fallback (fp32 tables)
__global__ __launch_bounds__(1024) void k_coef_f32(const float* __restrict__ hidden,
                                                   const float* __restrict__ down,
                                                   const int* __restrict__ tIdx,
                                                   const float* __restrict__ tW,
                                                   float* __restrict__ coef)
{
    __shared__ __align__(16) float hs[1024];
    __shared__ int   eidx[128];
    __shared__ float wv[128];
    const int t = blockIdx.x;
    const int tid = threadIdx.x;
    hs[tid] = hidden[(size_t)t * 1024 + tid];
    if (tid < 128) {
        eidx[tid] = tIdx[(size_t)t * 128 + tid];
        wv[tid]   = tW[(size_t)t * 128 + tid];
    }
    __syncthreads();
    const int wave = tid >> 6, lane = tid & 63;
#pragma unroll 2
    for (int i = 0; i < 8; i++) {
        const int p = wave * 8 + i;
        const float4* dp = (const float4*)(down + (size_t)eidx[p] * 1024);
        float sum = 0.f;
#pragma unroll
        for (int c = 0; c < 4; c++) {
            float4 dv = dp[lane + 64 * c];
            float4 hv = *(const float4*)(hs + (lane + 64 * c) * 4);
            sum += dv.x * hv.x + dv.y * hv.y + dv.z * hv.z + dv.w * hv.w;
        }
        for (int off = 32; off; off >>= 1) sum += __shfl_down(sum, off);
        if (lane == 0) {
            float x = sum;
            float g = 0.5f * x * (1.0f + erff(x * 0.70710678118654752f));
            coef[(size_t)t * 128 + p] = wv[p] * g;
        }
    }
}

// K5b fallback (fp32 tables)
__global__ __launch_bounds__(256) void k_accum_f32(const float* __restrict__ up,
                                                   const int* __restrict__ tIdx,
                                                   const float* __restrict__ coef,
                                                   float* __restrict__ out)
{
    __shared__ float cf[128];
    __shared__ int   ei[128];
    const int t = blockIdx.x >> 2;
    const int c = blockIdx.x & 3;
    const int tid = threadIdx.x;
    if (tid < 128) {
        cf[tid] = coef[(size_t)t * 128 + tid];
        ei[tid] = tIdx[(size_t)t * 128 + tid];
    }
    __syncthreads();
    const int j = c * 256 + tid;
    float acc = 0.f;
#pragma unroll 8
    for (int p = 0; p < 128; p++)
        acc = fmaf(cf[p], up[(size_t)ei[p] * 1024 + j], acc);
    out[(size_t)t * 1024 + j] = acc;
}

// ---------------------------------------------------------------------------
// Fallback fused launch (fp32 qproj 64x64 full-K + keynorm) — ws too small.
// ---------------------------------------------------------------------------
__global__ __launch_bounds__(256) void k_fall1(
    const float* __restrict__ A, const float* __restrict__ W,
    float* __restrict__ qp,
    const float* __restrict__ sk0, const float* __restrict__ sk1,
    float* __restrict__ k0n, float* __restrict__ k1n)
{
    __shared__ float smem[2 * 32 * 68];
    const int bid = blockIdx.x;
    const int tid = threadIdx.x;

    if (bid < 512) {
        float* As = smem;
        float* Bs = smem + 32 * 68;
        const int m0 = (bid >> 5) * 64;
        const int n0 = (bid & 31) * 64;
        const int aM  = tid >> 3;
        const int aK4 = (tid & 7) * 4;
        const int bK  = tid >> 4;
        const int bN4 = (tid & 15) * 4;
        const int ty  = tid >> 4;
        const int tx  = tid & 15;
        float acc[4][4] = {};
        for (int kk = 0; kk < 1024; kk += 32) {
            __syncthreads();
#pragma unroll
            for (int p = 0; p < 2; p++) {
                int m = aM + 32 * p;
                float4 v = *(const float4*)(A + (size_t)(m0 + m) * DDIM + kk + aK4);
                As[(aK4 + 0) * 68 + m] = v.x; As[(aK4 + 1) * 68 + m] = v.y;
                As[(aK4 + 2) * 68 + m] = v.z; As[(aK4 + 3) * 68 + m] = v.w;
            }
#pragma unroll
            for (int p = 0; p < 2; p++) {
                int k = bK + 16 * p;
                float4 v = *(const float4*)(W + (size_t)(kk + k) * HQD + n0 + bN4);
                *(float4*)&Bs[k * 68 + bN4] = v;
            }
            __syncthreads();
#pragma unroll
            for (int k = 0; k < 32; k++) {
                float a[4], b[4];
                *(float4*)(a) = *(const float4*)&As[k * 68 + ty * 4];
                *(float4*)(b) = *(const float4*)&Bs[k * 68 + tx * 4];
#pragma unroll
                for (int i = 0; i < 4; i++)
#pragma unroll
                    for (int j = 0; j < 4; j++)
                        acc[i][j] = fmaf(a[i], b[j], acc[i][j]);
            }
        }
#pragma unroll
        for (int i = 0; i < 4; i++) {
            int m = m0 + ty * 4 + i;
            float4 r;
            r.x = acc[i][0]; r.y = acc[i][1]; r.z = acc[i][2]; r.w = acc[i][3];
            *(float4*)(qp + (size_t)m * HQD + n0 + tx * 4) = r;
        }
    } else {
        const int b2 = bid - 512;
        const int sub = tid >> 7;
        const int col = tid & 127;
        const int gr = b2 * 2 + sub;
        const float* src = (gr < 128) ? sk0 : sk1;
        float* dst = (gr < 128) ? k0n : k1n;
        const int row = gr & 127;
        float v = src[row * 128 + col];
        float sq = v * v;
        for (int off = 32; off; off >>= 1) sq += __shfl_down(sq, off);
        if ((tid & 63) == 0) smem[tid >> 6] = sq;
        __syncthreads();
        if ((tid & 127) == 0) {
            float n = sqrtf(smem[tid >> 6] + smem[(tid >> 6) + 1]);
            smem[8 + sub] = 1.0f / fmaxf(n, 1e-12f);
        }
        __syncthreads();
        dst[row * 128 + col] = v * smem[8 + sub];
    }
}

// ---------------------------------------------------------------------------
extern "C" void kernel_launch(void* const* d_in, const int* in_sizes, int n_in,
                              void* d_out, int out_size, void* d_ws, size_t ws_size,
                              hipStream_t stream)
{
    const float* hidden = (const float*)d_in[0];
    const float* Wq     = (const float*)d_in[1];
    const float* bq     = (const float*)d_in[2];
    const float* gamma  = (const float*)d_in[3];
    const float* beta   = (const float*)d_in[4];
    const float* sk0    = (const float*)d_in[5];
    const float* sk1    = (const float*)d_in[6];
    const float* down   = (const float*)d_in[7];
    const float* up     = (const float*)d_in[8];
    float* out = (float*)d_out;

    float* ws = (float*)d_ws;
    size_t o = 0;
    float* qp    = ws + o; o += (size_t)TOKENS * HQD;      // 2M floats
    float* ps    = ws + o; o += 512 * 256;
    float* pq    = ws + o; o += 512 * 256;
    float* meanb = ws + o; o += 256;
    float* scaleb= ws + o; o += 256;
    float* k0n   = ws + o; o += NKEY * 128;
    float* k1n   = ws + o; o += NKEY * 128;
    float* s0    = ws + o; o += (size_t)NROWS * 128;
    float* s1    = ws + o; o += (size_t)NROWS * 128;
    float* tW    = ws + o; o += (size_t)NROWS * TOPK;
    int*   tIdx  = (int*)(ws + o); o += (size_t)NROWS * TOPK;
    float* coef  = ws + o; o += (size_t)TOKENS * 128;
    ushort_t* downb = (ushort_t*)(ws + o); o += (size_t)16384 * 1024 / 2;
    ushort_t* upb   = (ushort_t*)(ws + o); o += (size_t)16384 * 1024 / 2;
    ushort_t* Ab    = (ushort_t*)(ws + o); o += (size_t)1024 * 2048 / 2;   // 1M floats
    ushort_t* Wt    = (ushort_t*)(ws + o); o += (size_t)2048 * 2048 / 2;   // 2M floats
    const int useBF = (ws_size >= o * sizeof(float)) ? 1 : 0;
    const float qsc = useBF ? QINVS : 1.0f;

    if (useBF) {
        k_prep1 <<<768, 256, 0, stream>>>(hidden, Wq, Ab, Wt, sk0, sk1, k0n, k1n);
        k_fused2<<<1536, 256, 0, stream>>>(Ab, Wt, qp, down, up, downb, upb);
        k_bnstat1<<<512, 256, 0, stream>>>(qp, bq, ps, pq, qsc);
        k_bnstat2<<<8, 256, 0, stream>>>(ps, pq, gamma, meanb, scaleb);
        k_scores <<<768, 256, 0, stream>>>(qp, bq, meanb, scaleb, beta,
                                           k0n, k1n, s0, s1, qsc,
                                           down, up, downb, upb);
        k_topk   <<<2560, 256, 0, stream>>>(s0, s1, tIdx, tW, down, up, downb, upb);
        k_mlp_bf <<<TOKENS, 1024, 0, stream>>>(hidden, downb, upb, tIdx, tW, out);
    } else {
        k_fall1 <<<640, 256, 0, stream>>>(hidden, Wq, qp, sk0, sk1, k0n, k1n);
        k_bnstat1<<<512, 256, 0, stream>>>(qp, bq, ps, pq, qsc);
        k_bnstat2<<<8, 256, 0, stream>>>(ps, pq, gamma, meanb, scaleb);
        k_scores <<<256, 256, 0, stream>>>(qp, bq, meanb, scaleb, beta,
                                           k0n, k1n, s0, s1, qsc,
                                           down, up, downb, upb);
        k_topk   <<<2048, 256, 0, stream>>>(s0, s1, tIdx, tW, down, up, downb, upb);
        k_coef_f32 <<<TOKENS, 1024, 0, stream>>>(hidden, down, tIdx, tW, coef);
        k_accum_f32<<<4096, 256, 0, stream>>>(up, tIdx, coef, out);
    }
}